// Round 4
// baseline (1153.528 us; speedup 1.0000x reference)
//
#include <hip/hip_runtime.h>
#include <cstdint>
#include <cmath>

typedef unsigned short u16;
typedef __attribute__((ext_vector_type(4))) float f32x4;
typedef __attribute__((ext_vector_type(8))) _Float16 f16x8;

#define GPTR(p) ((__attribute__((address_space(1))) void*)(uintptr_t)(p))
#define LPTR(p) ((__attribute__((address_space(3))) void*)(uint32_t)(uintptr_t)(p))

__device__ __forceinline__ u16 f2h(float f) {
  const _Float16 h = (_Float16)f;   // RNE
  return __builtin_bit_cast(u16, h);
}
__device__ __forceinline__ float h2f(u16 v) {
  return (float)__builtin_bit_cast(_Float16, v);
}

// ---------------- diagnostic fill (ws too small; exponent-coded, bf16-rounding-proof) ----------------
__global__ __launch_bounds__(256) void fill_kernel(float* __restrict__ p, float v, long n) {
  const long i = (long)blockIdx.x * 256 + threadIdx.x;
  if (i < n) p[i] = v;
}

// ---------------- fp32 -> fp16 convert (8 elems/thread) ----------------
__global__ __launch_bounds__(256) void cvt_kernel(const float* __restrict__ src, u16* __restrict__ dst) {
  const long i = ((long)blockIdx.x * 256 + threadIdx.x) * 8;
  const float4 a = *(const float4*)&src[i];
  const float4 b = *(const float4*)&src[i + 4];
  uint4 o;
  o.x = (uint32_t)f2h(a.x) | ((uint32_t)f2h(a.y) << 16);
  o.y = (uint32_t)f2h(a.z) | ((uint32_t)f2h(a.w) << 16);
  o.z = (uint32_t)f2h(b.x) | ((uint32_t)f2h(b.y) << 16);
  o.w = (uint32_t)f2h(b.z) | ((uint32_t)f2h(b.w) << 16);
  *(uint4*)&dst[i] = o;
}

// ---------------- fp32 [R][C] -> fp16 [C][R] transpose-convert ----------------
__global__ void transpose_kernel(const float* __restrict__ src, u16* __restrict__ dst, int R, int C) {
  __shared__ float tile[32][33];
  const int bx = blockIdx.x * 32, by = blockIdx.y * 32;
  const int tx = threadIdx.x, ty = threadIdx.y;  // block (32,8)
#pragma unroll
  for (int i = 0; i < 32; i += 8) tile[ty + i][tx] = src[(long)(by + ty + i) * C + bx + tx];
  __syncthreads();
#pragma unroll
  for (int i = 0; i < 32; i += 8) dst[(long)(bx + ty + i) * R + by + tx] = f2h(tile[tx][ty + i]);
}

// ---------------- fp16 MFMA GEMM, m97 structure (R2-proven skeleton) ----------------
// C = A @ Bt^T (+bias) (+resH) (leaky) -> fp32 / fp16 (+lo split) / fp16-transposed.
__global__ __launch_bounds__(256) void gemm_f16(
    const u16* __restrict__ A, const u16* __restrict__ Bt,
    float* __restrict__ outF, u16* __restrict__ outH, u16* __restrict__ outH2,
    u16* __restrict__ outT,
    const float* __restrict__ bias, const u16* __restrict__ resH,
    int act,
    int K, int lda, int ldb, int ldc, int ldt,
    long strA, long strB, long strC, long strT)
{
  __shared__ alignas(16) u16 sA[128 * 32];
  __shared__ alignas(16) u16 sB[128 * 32];

  const int tid = threadIdx.x;
  const int lane = tid & 63;
  const int wv = tid >> 6;
  const int wr = wv >> 1, wc = wv & 1;
  const int fr = lane & 15, fg = lane >> 4;

  const int z = blockIdx.z;
  const int rowBase = blockIdx.y * 128;
  const int colBase = blockIdx.x * 128;

  const u16* Ab = A + (long)z * strA;
  const u16* Bb = Bt + (long)z * strB;

  const int srow = wv * 32 + (lane >> 2);
  const int scol = (lane & 3) * 8;
  const u16* gA0 = Ab + (long)(rowBase + srow) * lda + scol;
  const u16* gA1 = gA0 + (long)16 * lda;
  const u16* gB0 = Bb + (long)(colBase + srow) * ldb + scol;
  const u16* gB1 = gB0 + (long)16 * ldb;
  u16* lA0 = &sA[wv * 1024];
  u16* lA1 = lA0 + 512;
  u16* lB0 = &sB[wv * 1024];
  u16* lB1 = lB0 + 512;

  f32x4 acc[4][4];
#pragma unroll
  for (int m = 0; m < 4; ++m)
#pragma unroll
    for (int n = 0; n < 4; ++n) acc[m][n] = (f32x4){0.f, 0.f, 0.f, 0.f};

  const int nk = K >> 5;
  __builtin_amdgcn_global_load_lds(GPTR(gA0), LPTR(lA0), 16, 0, 0);
  __builtin_amdgcn_global_load_lds(GPTR(gA1), LPTR(lA1), 16, 0, 0);
  __builtin_amdgcn_global_load_lds(GPTR(gB0), LPTR(lB0), 16, 0, 0);
  __builtin_amdgcn_global_load_lds(GPTR(gB1), LPTR(lB1), 16, 0, 0);

  for (int kt = 0; kt < nk; ++kt) {
    asm volatile("s_waitcnt vmcnt(0)" ::: "memory");
    __syncthreads();

    f16x8 af[4], bfr[4];
#pragma unroll
    for (int m = 0; m < 4; ++m) af[m] = *(const f16x8*)&sA[(wr * 64 + m * 16 + fr) * 32 + fg * 8];
#pragma unroll
    for (int n = 0; n < 4; ++n) bfr[n] = *(const f16x8*)&sB[(wc * 64 + n * 16 + fr) * 32 + fg * 8];
#pragma unroll
    for (int m = 0; m < 4; ++m)
#pragma unroll
      for (int n = 0; n < 4; ++n)
        acc[m][n] = __builtin_amdgcn_mfma_f32_16x16x32_f16(af[m], bfr[n], acc[m][n], 0, 0, 0);

    if (kt + 1 < nk) {
      __syncthreads();
      const long o = (long)(kt + 1) * 32;
      __builtin_amdgcn_global_load_lds(GPTR(gA0 + o), LPTR(lA0), 16, 0, 0);
      __builtin_amdgcn_global_load_lds(GPTR(gA1 + o), LPTR(lA1), 16, 0, 0);
      __builtin_amdgcn_global_load_lds(GPTR(gB0 + o), LPTR(lB0), 16, 0, 0);
      __builtin_amdgcn_global_load_lds(GPTR(gB1 + o), LPTR(lB1), 16, 0, 0);
    }
  }

  float* oF = outF ? outF + (long)z * strC : nullptr;
  u16* oH = outH ? outH + (long)z * strC : nullptr;
  u16* oH2 = outH2 ? outH2 + (long)z * strC : nullptr;
  u16* oT = outT ? outT + (long)z * strT : nullptr;
  const u16* rH = resH ? resH + (long)z * strC : nullptr;

#pragma unroll
  for (int n = 0; n < 4; ++n) {
    const int col = colBase + wc * 64 + n * 16 + fr;
    const float bc = bias ? bias[col] : 0.f;
#pragma unroll
    for (int m = 0; m < 4; ++m) {
      const int row0 = rowBase + wr * 64 + m * 16 + fg * 4;
      float y[4];
#pragma unroll
      for (int j = 0; j < 4; ++j) {
        float val = acc[m][n][j] + bc;
        if (rH) val += h2f(rH[(long)(row0 + j) * ldc + col]);
        if (act) val = val > 0.f ? val : 0.01f * val;
        y[j] = val;
        if (oF) oF[(long)(row0 + j) * ldc + col] = val;
        if (oH) {
          const _Float16 hi = (_Float16)val;
          oH[(long)(row0 + j) * ldc + col] = __builtin_bit_cast(u16, hi);
          if (oH2) oH2[(long)(row0 + j) * ldc + col] = f2h(val - (float)hi);
        }
      }
      if (oT) {
        uint2 pk;
        pk.x = (uint32_t)f2h(y[0]) | ((uint32_t)f2h(y[1]) << 16);
        pk.y = (uint32_t)f2h(y[2]) | ((uint32_t)f2h(y[3]) << 16);
        *(uint2*)&oT[(long)col * ldt + row0] = pk;
      }
    }
  }
}

// ---------------- split-fp16 3-term GEMM: scores = (Ah+Al) @ (Bh+Bl)^T -> fp16 ----------------
__global__ __launch_bounds__(256) void gemm_qk3(
    const u16* __restrict__ Ah, const u16* __restrict__ Al,
    const u16* __restrict__ Bh, const u16* __restrict__ Bl,
    u16* __restrict__ outH,
    int K, int lda, int ldb, int ldc,
    long strA, long strB, long strC)
{
  __shared__ alignas(16) u16 sAh[128 * 32];
  __shared__ alignas(16) u16 sAl[128 * 32];
  __shared__ alignas(16) u16 sBh[128 * 32];
  __shared__ alignas(16) u16 sBl[128 * 32];

  const int tid = threadIdx.x;
  const int lane = tid & 63;
  const int wv = tid >> 6;
  const int wr = wv >> 1, wc = wv & 1;
  const int fr = lane & 15, fg = lane >> 4;

  const int z = blockIdx.z;
  const int rowBase = blockIdx.y * 128;
  const int colBase = blockIdx.x * 128;

  const int srow = wv * 32 + (lane >> 2);
  const int scol = (lane & 3) * 8;
  const long aoff = (long)(rowBase + srow) * lda + scol + (long)z * strA;
  const long boff = (long)(colBase + srow) * ldb + scol + (long)z * strB;
  const u16* gAh0 = Ah + aoff; const u16* gAh1 = gAh0 + (long)16 * lda;
  const u16* gAl0 = Al + aoff; const u16* gAl1 = gAl0 + (long)16 * lda;
  const u16* gBh0 = Bh + boff; const u16* gBh1 = gBh0 + (long)16 * ldb;
  const u16* gBl0 = Bl + boff; const u16* gBl1 = gBl0 + (long)16 * ldb;
  u16* lAh0 = &sAh[wv * 1024]; u16* lAh1 = lAh0 + 512;
  u16* lAl0 = &sAl[wv * 1024]; u16* lAl1 = lAl0 + 512;
  u16* lBh0 = &sBh[wv * 1024]; u16* lBh1 = lBh0 + 512;
  u16* lBl0 = &sBl[wv * 1024]; u16* lBl1 = lBl0 + 512;

  f32x4 acc[4][4];
#pragma unroll
  for (int m = 0; m < 4; ++m)
#pragma unroll
    for (int n = 0; n < 4; ++n) acc[m][n] = (f32x4){0.f, 0.f, 0.f, 0.f};

  const int nk = K >> 5;
  __builtin_amdgcn_global_load_lds(GPTR(gAh0), LPTR(lAh0), 16, 0, 0);
  __builtin_amdgcn_global_load_lds(GPTR(gAh1), LPTR(lAh1), 16, 0, 0);
  __builtin_amdgcn_global_load_lds(GPTR(gAl0), LPTR(lAl0), 16, 0, 0);
  __builtin_amdgcn_global_load_lds(GPTR(gAl1), LPTR(lAl1), 16, 0, 0);
  __builtin_amdgcn_global_load_lds(GPTR(gBh0), LPTR(lBh0), 16, 0, 0);
  __builtin_amdgcn_global_load_lds(GPTR(gBh1), LPTR(lBh1), 16, 0, 0);
  __builtin_amdgcn_global_load_lds(GPTR(gBl0), LPTR(lBl0), 16, 0, 0);
  __builtin_amdgcn_global_load_lds(GPTR(gBl1), LPTR(lBl1), 16, 0, 0);

  for (int kt = 0; kt < nk; ++kt) {
    asm volatile("s_waitcnt vmcnt(0)" ::: "memory");
    __syncthreads();

    f16x8 ah[4], al[4], bh[4], bl[4];
#pragma unroll
    for (int m = 0; m < 4; ++m) {
      const int r = (wr * 64 + m * 16 + fr) * 32 + fg * 8;
      ah[m] = *(const f16x8*)&sAh[r];
      al[m] = *(const f16x8*)&sAl[r];
    }
#pragma unroll
    for (int n = 0; n < 4; ++n) {
      const int r = (wc * 64 + n * 16 + fr) * 32 + fg * 8;
      bh[n] = *(const f16x8*)&sBh[r];
      bl[n] = *(const f16x8*)&sBl[r];
    }
#pragma unroll
    for (int m = 0; m < 4; ++m)
#pragma unroll
      for (int n = 0; n < 4; ++n) {
        acc[m][n] = __builtin_amdgcn_mfma_f32_16x16x32_f16(al[m], bh[n], acc[m][n], 0, 0, 0);
        acc[m][n] = __builtin_amdgcn_mfma_f32_16x16x32_f16(ah[m], bl[n], acc[m][n], 0, 0, 0);
        acc[m][n] = __builtin_amdgcn_mfma_f32_16x16x32_f16(ah[m], bh[n], acc[m][n], 0, 0, 0);
      }

    if (kt + 1 < nk) {
      __syncthreads();
      const long o = (long)(kt + 1) * 32;
      __builtin_amdgcn_global_load_lds(GPTR(gAh0 + o), LPTR(lAh0), 16, 0, 0);
      __builtin_amdgcn_global_load_lds(GPTR(gAh1 + o), LPTR(lAh1), 16, 0, 0);
      __builtin_amdgcn_global_load_lds(GPTR(gAl0 + o), LPTR(lAl0), 16, 0, 0);
      __builtin_amdgcn_global_load_lds(GPTR(gAl1 + o), LPTR(lAl1), 16, 0, 0);
      __builtin_amdgcn_global_load_lds(GPTR(gBh0 + o), LPTR(lBh0), 16, 0, 0);
      __builtin_amdgcn_global_load_lds(GPTR(gBh1 + o), LPTR(lBh1), 16, 0, 0);
      __builtin_amdgcn_global_load_lds(GPTR(gBl0 + o), LPTR(lBl0), 16, 0, 0);
      __builtin_amdgcn_global_load_lds(GPTR(gBl1 + o), LPTR(lBl1), 16, 0, 0);
    }
  }

  u16* oH = outH + (long)z * strC;
#pragma unroll
  for (int n = 0; n < 4; ++n) {
    const int col = colBase + wc * 64 + n * 16 + fr;
#pragma unroll
    for (int m = 0; m < 4; ++m) {
      const int row0 = rowBase + wr * 64 + m * 16 + fg * 4;
#pragma unroll
      for (int j = 0; j < 4; ++j) oH[(long)(row0 + j) * ldc + col] = f2h(acc[m][n][j]);
    }
  }
}

// ---------------- row softmax: fp16 [rows][2048] -> fp16 probs, IN-PLACE (R2-proven) ----------------
__global__ __launch_bounds__(256) void softmax_kernel(u16* __restrict__ buf) {
  __shared__ float red[16];
  const long base = (long)blockIdx.x * 2048;
  const int t = threadIdx.x, lane = t & 63, wv = t >> 6;
  const uint4 a = *(const uint4*)&buf[base + t * 8];   // 8 fp16
  float v[8] = {h2f((u16)(a.x & 0xFFFF)), h2f((u16)(a.x >> 16)),
                h2f((u16)(a.y & 0xFFFF)), h2f((u16)(a.y >> 16)),
                h2f((u16)(a.z & 0xFFFF)), h2f((u16)(a.z >> 16)),
                h2f((u16)(a.w & 0xFFFF)), h2f((u16)(a.w >> 16))};
  float mx = v[0];
#pragma unroll
  for (int i = 1; i < 8; ++i) mx = fmaxf(mx, v[i]);
#pragma unroll
  for (int o = 32; o; o >>= 1) mx = fmaxf(mx, __shfl_xor(mx, o));
  if (lane == 0) red[wv] = mx;
  __syncthreads();
  mx = fmaxf(fmaxf(red[0], red[1]), fmaxf(red[2], red[3]));
  float s = 0.f;
#pragma unroll
  for (int i = 0; i < 8; ++i) { v[i] = __expf(v[i] - mx); s += v[i]; }
#pragma unroll
  for (int o = 32; o; o >>= 1) s += __shfl_xor(s, o);
  if (lane == 0) red[8 + wv] = s;
  __syncthreads();   // orders all reads before the in-place writes
  const float inv = 1.f / (red[8] + red[9] + red[10] + red[11]);
  uint4 o4;
  o4.x = (uint32_t)f2h(v[0] * inv) | ((uint32_t)f2h(v[1] * inv) << 16);
  o4.y = (uint32_t)f2h(v[2] * inv) | ((uint32_t)f2h(v[3] * inv) << 16);
  o4.z = (uint32_t)f2h(v[4] * inv) | ((uint32_t)f2h(v[5] * inv) << 16);
  o4.w = (uint32_t)f2h(v[6] * inv) | ((uint32_t)f2h(v[7] * inv) << 16);
  *(uint4*)&buf[base + t * 8] = o4;
}

// ---------------- LayerNorm: fp32 OR fp16 input, optional fp32 residual ----------------
template <int W>
__global__ __launch_bounds__(256) void ln_kernel(
    const float* __restrict__ inF, const u16* __restrict__ inH, const float* __restrict__ resF,
    const float* __restrict__ gam, const float* __restrict__ bet,
    float* __restrict__ outF, u16* __restrict__ outH)
{
  constexpr int NV = W / 1024;
  __shared__ float red[16];
  const long base = (long)blockIdx.x * W;
  const int t = threadIdx.x, lane = t & 63, wv = t >> 6;
  float v[NV * 4];
  float s = 0.f, ss = 0.f;
#pragma unroll
  for (int c = 0; c < NV; ++c) {
    const int idx = (t + c * 256) * 4;
    float4 a;
    if (inF) a = *(const float4*)&inF[base + idx];
    else {
      const uint2 r = *(const uint2*)&inH[base + idx];
      a.x = h2f((u16)(r.x & 0xFFFF)); a.y = h2f((u16)(r.x >> 16));
      a.z = h2f((u16)(r.y & 0xFFFF)); a.w = h2f((u16)(r.y >> 16));
    }
    if (resF) {
      const float4 r4 = *(const float4*)&resF[base + idx];
      a.x += r4.x; a.y += r4.y; a.z += r4.z; a.w += r4.w;
    }
    v[c * 4 + 0] = a.x; v[c * 4 + 1] = a.y; v[c * 4 + 2] = a.z; v[c * 4 + 3] = a.w;
    s += a.x + a.y + a.z + a.w;
    ss += a.x * a.x + a.y * a.y + a.z * a.z + a.w * a.w;
  }
#pragma unroll
  for (int o = 32; o; o >>= 1) { s += __shfl_xor(s, o); ss += __shfl_xor(ss, o); }
  if (lane == 0) { red[wv] = s; red[8 + wv] = ss; }
  __syncthreads();
  s = red[0] + red[1] + red[2] + red[3];
  ss = red[8] + red[9] + red[10] + red[11];
  const float mean = s * (1.f / W);
  const float rstd = rsqrtf(ss * (1.f / W) - mean * mean + 1e-5f);
#pragma unroll
  for (int c = 0; c < NV; ++c) {
    const int idx = (t + c * 256) * 4;
    const float4 g4 = *(const float4*)&gam[idx];
    const float4 b4 = *(const float4*)&bet[idx];
    const float y0 = (v[c * 4 + 0] - mean) * rstd * g4.x + b4.x;
    const float y1 = (v[c * 4 + 1] - mean) * rstd * g4.y + b4.y;
    const float y2 = (v[c * 4 + 2] - mean) * rstd * g4.z + b4.z;
    const float y3 = (v[c * 4 + 3] - mean) * rstd * g4.w + b4.w;
    if (outF) { float4 o4 = {y0, y1, y2, y3}; *(float4*)&outF[base + idx] = o4; }
    if (outH) {
      uint2 p;
      p.x = (uint32_t)f2h(y0) | ((uint32_t)f2h(y1) << 16);
      p.y = (uint32_t)f2h(y2) | ((uint32_t)f2h(y3) << 16);
      *(uint2*)&outH[base + idx] = p;
    }
  }
}

// ============================== host ==============================
extern "C" void kernel_launch(void* const* d_in, const int* in_sizes, int n_in,
                              void* d_out, int out_size, void* d_ws, size_t ws_size,
                              hipStream_t stream) {
  const float* x   = (const float*)d_in[0];
  const float* wq  = (const float*)d_in[1];
  const float* bq  = (const float*)d_in[2];
  const float* wk  = (const float*)d_in[3];
  const float* bk  = (const float*)d_in[4];
  const float* wv  = (const float*)d_in[5];
  const float* bv  = (const float*)d_in[6];
  const float* w0  = (const float*)d_in[7];
  const float* b0  = (const float*)d_in[8];
  const float* w1  = (const float*)d_in[9];
  const float* b1  = (const float*)d_in[10];
  const float* lng = (const float*)d_in[11];
  const float* lnb = (const float*)d_in[12];
  const float* w2  = (const float*)d_in[13];
  const float* b2  = (const float*)d_in[14];
  const float* n1g = (const float*)d_in[15];
  const float* n1b = (const float*)d_in[16];
  const float* n2g = (const float*)d_in[17];
  const float* n2b = (const float*)d_in[18];
  float* out = (float*)d_out;

  const size_t NEED = 251658240u;  // 240 MiB — R2-proven to fit
  if (ws_size < NEED) {
    // exponent-coded sentinel: absmax ~= 2^(ws_MiB/32), survives bf16 rounding
    int k = (int)(ws_size >> 25); if (k > 60) k = 60;
    const float sentinel = ldexpf(1.0f, k + 4);
    fill_kernel<<<dim3((out_size + 255) / 256), dim3(256), 0, stream>>>(out, sentinel, out_size);
    return;
  }
  char* ws = (char*)d_ws;
  // ---- 240 MiB overlay (liveness-audited) ----
  u16* xb    = (u16*)(ws);                    // [0..32)   x fp16; dead after QKV
  u16* sc    = (u16*)(ws);                    // [0..64)   fp16 scores -> fp16 probs in-place
  u16* hb    = (u16*)(ws);                    // [0..64)   LN(h) fp16 (step 9; sc dead)
  u16* qhi   = (u16*)(ws + 67108864);         // [64..96)  dead after qk3 -> attnb
  u16* attnb = qhi;
  u16* qlo   = (u16*)(ws + 100663296);        // [96..128) dead after qk3 -> tb
  u16* tb    = qlo;
  u16* khi   = (u16*)(ws + 134217728);        // [128..160) dead after qk3 -> eb
  u16* eb    = khi;
  u16* klo   = (u16*)(ws + 167772160);        // [160..192) dead after qk3 ┐ hraw [160..224)
  u16* hraw  = klo;                           //                            │
  u16* vT    = (u16*)(ws + 201326592);        // [192..224) dead after PV  ┘
  float* uF  = (float*)(ws + 67108864);       // [64..128) fp32 (step 10; attnb+tb dead)
  u16* wqT   = (u16*)(ws + 234881024);        // [224..240) weights fp16
  u16* wkT   = (u16*)(ws + 236978176);
  u16* wvT   = (u16*)(ws + 239075328);
  u16* w0T   = (u16*)(ws + 241172480);
  u16* w1T   = (u16*)(ws + 243269632);
  u16* w2T   = (u16*)(ws + 247463936);

  const dim3 b256(256);
  const dim3 tblk(32, 8);

  // 1) convert x -> fp16; transpose-convert weights to [out][in] fp16
  cvt_kernel<<<dim3(8192), b256, 0, stream>>>(x, xb);
  transpose_kernel<<<dim3(32, 32), tblk, 0, stream>>>(wq, wqT, 1024, 1024);
  transpose_kernel<<<dim3(32, 32), tblk, 0, stream>>>(wk, wkT, 1024, 1024);
  transpose_kernel<<<dim3(32, 32), tblk, 0, stream>>>(wv, wvT, 1024, 1024);
  transpose_kernel<<<dim3(32, 32), tblk, 0, stream>>>(w0, w0T, 1024, 1024);
  transpose_kernel<<<dim3(64, 32), tblk, 0, stream>>>(w1, w1T, 1024, 2048);
  transpose_kernel<<<dim3(32, 64), tblk, 0, stream>>>(w2, w2T, 2048, 1024);

  // 2) q, k in split hi/lo fp16; v fp16 transposed -> vT[1024][16384]
  gemm_f16<<<dim3(8, 128, 1), b256, 0, stream>>>(xb, wqT, nullptr, qhi, qlo, nullptr, bq, nullptr,
      0, 1024, 1024, 1024, 1024, 0, 0, 0, 0, 0);
  gemm_f16<<<dim3(8, 128, 1), b256, 0, stream>>>(xb, wkT, nullptr, khi, klo, nullptr, bk, nullptr,
      0, 1024, 1024, 1024, 1024, 0, 0, 0, 0, 0);
  gemm_f16<<<dim3(8, 128, 1), b256, 0, stream>>>(xb, wvT, nullptr, nullptr, nullptr, vT, bv, nullptr,
      0, 1024, 1024, 1024, 1024, 16384, 0, 0, 0, 0);

  // 3) scores[b] = (qhi+qlo) @ (khi+klo)^T -> fp16 (fp32 accum, 3 MFMA terms)
  gemm_qk3<<<dim3(16, 16, 8), b256, 0, stream>>>(qhi, qlo, khi, klo, sc,
      1024, 1024, 1024, 2048, 2097152, 2097152, 4194304);

  // 4) softmax rows (fp16 -> fp16 probs, in-place)
  softmax_kernel<<<dim3(16384), b256, 0, stream>>>(sc);

  // 5) attn[b] = probs_b @ v_b -> fp16 into attnb (qhi region, dead)
  gemm_f16<<<dim3(8, 16, 8), b256, 0, stream>>>(sc, vT, nullptr, attnb, nullptr, nullptr, nullptr, nullptr,
      0, 2048, 2048, 16384, 1024, 0, 4194304, 2048, 2097152, 0);

  // 6) tb = LN(x + attn; n1) -> fp16 (qlo region, dead)
  ln_kernel<1024><<<dim3(16384), b256, 0, stream>>>(nullptr, attnb, x, n1g, n1b, nullptr, tb);

  // 7) eb = tb @ w0 + b0 -> fp16 (khi region, dead)
  gemm_f16<<<dim3(8, 128, 1), b256, 0, stream>>>(tb, w0T, nullptr, eb, nullptr, nullptr, b0, nullptr,
      0, 1024, 1024, 1024, 1024, 0, 0, 0, 0, 0);

  // 8) hraw = leaky(eb @ w1 + b1) -> fp16 (klo+vT region, dead)
  gemm_f16<<<dim3(16, 128, 1), b256, 0, stream>>>(eb, w1T, nullptr, hraw, nullptr, nullptr, b1, nullptr,
      1, 1024, 1024, 1024, 2048, 0, 0, 0, 0, 0);

  // 9) hb = LN(hraw; ln) -> fp16 (sc region, dead)
  ln_kernel<2048><<<dim3(16384), b256, 0, stream>>>(nullptr, hraw, nullptr, lng, lnb, nullptr, hb);

  // 10) uF = leaky(hb @ w2 + b2 + eb) -> fp32 (attnb+tb region, dead)
  gemm_f16<<<dim3(8, 128, 1), b256, 0, stream>>>(hb, w2T, uF, nullptr, nullptr, nullptr, b2, eb,
      1, 2048, 2048, 2048, 1024, 0, 0, 0, 0, 0);

  // 11) out = LN(uF; n2) fp32
  ln_kernel<1024><<<dim3(16384), b256, 0, stream>>>(uF, nullptr, nullptr, n2g, n2b, out, nullptr);
}

// Round 5
// 1028.724 us; speedup vs baseline: 1.1213x; 1.1213x over previous
//
#include <hip/hip_runtime.h>
#include <cstdint>
#include <cmath>

typedef unsigned short u16;
typedef __attribute__((ext_vector_type(4))) float f32x4;
typedef __attribute__((ext_vector_type(8))) _Float16 f16x8;

#define GPTR(p) ((__attribute__((address_space(1))) void*)(uintptr_t)(p))
#define LPTR(p) ((__attribute__((address_space(3))) void*)(uint32_t)(uintptr_t)(p))

__device__ __forceinline__ u16 f2h(float f) {
  const _Float16 h = (_Float16)f;   // RNE
  return __builtin_bit_cast(u16, h);
}
__device__ __forceinline__ float h2f(u16 v) {
  return (float)__builtin_bit_cast(_Float16, v);
}

// ---------------- diagnostic fill (ws too small; exponent-coded sentinel) ----------------
__global__ __launch_bounds__(256) void fill_kernel(float* __restrict__ p, float v, long n) {
  const long i = (long)blockIdx.x * 256 + threadIdx.x;
  if (i < n) p[i] = v;
}

// ---------------- fp32 -> fp16 convert (8 elems/thread) ----------------
__global__ __launch_bounds__(256) void cvt_kernel(const float* __restrict__ src, u16* __restrict__ dst) {
  const long i = ((long)blockIdx.x * 256 + threadIdx.x) * 8;
  const float4 a = *(const float4*)&src[i];
  const float4 b = *(const float4*)&src[i + 4];
  uint4 o;
  o.x = (uint32_t)f2h(a.x) | ((uint32_t)f2h(a.y) << 16);
  o.y = (uint32_t)f2h(a.z) | ((uint32_t)f2h(a.w) << 16);
  o.z = (uint32_t)f2h(b.x) | ((uint32_t)f2h(b.y) << 16);
  o.w = (uint32_t)f2h(b.z) | ((uint32_t)f2h(b.w) << 16);
  *(uint4*)&dst[i] = o;
}

// ---------------- fp32 [R][C] -> fp16 [C][R] transpose-convert ----------------
__global__ void transpose_kernel(const float* __restrict__ src, u16* __restrict__ dst, int R, int C) {
  __shared__ float tile[32][33];
  const int bx = blockIdx.x * 32, by = blockIdx.y * 32;
  const int tx = threadIdx.x, ty = threadIdx.y;  // block (32,8)
#pragma unroll
  for (int i = 0; i < 32; i += 8) tile[ty + i][tx] = src[(long)(by + ty + i) * C + bx + tx];
  __syncthreads();
#pragma unroll
  for (int i = 0; i < 32; i += 8) dst[(long)(bx + ty + i) * R + by + tx] = f2h(tile[tx][ty + i]);
}

// ---------------- fp16 MFMA GEMM, m97 structure (R4-proven skeleton) ----------------
// C = A @ Bt^T (+bias) (+resH) (leaky) -> fp32 / fp16 / fp16-transposed.
__global__ __launch_bounds__(256) void gemm_f16(
    const u16* __restrict__ A, const u16* __restrict__ Bt,
    float* __restrict__ outF, u16* __restrict__ outH, u16* __restrict__ outT,
    const float* __restrict__ bias, const u16* __restrict__ resH,
    int act,
    int K, int lda, int ldb, int ldc, int ldt,
    long strA, long strB, long strC, long strT)
{
  __shared__ alignas(16) u16 sA[128 * 32];
  __shared__ alignas(16) u16 sB[128 * 32];

  const int tid = threadIdx.x;
  const int lane = tid & 63;
  const int wv = tid >> 6;
  const int wr = wv >> 1, wc = wv & 1;
  const int fr = lane & 15, fg = lane >> 4;

  const int z = blockIdx.z;
  const int rowBase = blockIdx.y * 128;
  const int colBase = blockIdx.x * 128;

  const u16* Ab = A + (long)z * strA;
  const u16* Bb = Bt + (long)z * strB;

  const int srow = wv * 32 + (lane >> 2);
  const int scol = (lane & 3) * 8;
  const u16* gA0 = Ab + (long)(rowBase + srow) * lda + scol;
  const u16* gA1 = gA0 + (long)16 * lda;
  const u16* gB0 = Bb + (long)(colBase + srow) * ldb + scol;
  const u16* gB1 = gB0 + (long)16 * ldb;
  u16* lA0 = &sA[wv * 1024];
  u16* lA1 = lA0 + 512;
  u16* lB0 = &sB[wv * 1024];
  u16* lB1 = lB0 + 512;

  f32x4 acc[4][4];
#pragma unroll
  for (int m = 0; m < 4; ++m)
#pragma unroll
    for (int n = 0; n < 4; ++n) acc[m][n] = (f32x4){0.f, 0.f, 0.f, 0.f};

  const int nk = K >> 5;
  __builtin_amdgcn_global_load_lds(GPTR(gA0), LPTR(lA0), 16, 0, 0);
  __builtin_amdgcn_global_load_lds(GPTR(gA1), LPTR(lA1), 16, 0, 0);
  __builtin_amdgcn_global_load_lds(GPTR(gB0), LPTR(lB0), 16, 0, 0);
  __builtin_amdgcn_global_load_lds(GPTR(gB1), LPTR(lB1), 16, 0, 0);

  for (int kt = 0; kt < nk; ++kt) {
    asm volatile("s_waitcnt vmcnt(0)" ::: "memory");
    __syncthreads();

    f16x8 af[4], bfr[4];
#pragma unroll
    for (int m = 0; m < 4; ++m) af[m] = *(const f16x8*)&sA[(wr * 64 + m * 16 + fr) * 32 + fg * 8];
#pragma unroll
    for (int n = 0; n < 4; ++n) bfr[n] = *(const f16x8*)&sB[(wc * 64 + n * 16 + fr) * 32 + fg * 8];
#pragma unroll
    for (int m = 0; m < 4; ++m)
#pragma unroll
      for (int n = 0; n < 4; ++n)
        acc[m][n] = __builtin_amdgcn_mfma_f32_16x16x32_f16(af[m], bfr[n], acc[m][n], 0, 0, 0);

    if (kt + 1 < nk) {
      __syncthreads();
      const long o = (long)(kt + 1) * 32;
      __builtin_amdgcn_global_load_lds(GPTR(gA0 + o), LPTR(lA0), 16, 0, 0);
      __builtin_amdgcn_global_load_lds(GPTR(gA1 + o), LPTR(lA1), 16, 0, 0);
      __builtin_amdgcn_global_load_lds(GPTR(gB0 + o), LPTR(lB0), 16, 0, 0);
      __builtin_amdgcn_global_load_lds(GPTR(gB1 + o), LPTR(lB1), 16, 0, 0);
    }
  }

  float* oF = outF ? outF + (long)z * strC : nullptr;
  u16* oH = outH ? outH + (long)z * strC : nullptr;
  u16* oT = outT ? outT + (long)z * strT : nullptr;
  const u16* rH = resH ? resH + (long)z * strC : nullptr;

#pragma unroll
  for (int n = 0; n < 4; ++n) {
    const int col = colBase + wc * 64 + n * 16 + fr;
    const float bc = bias ? bias[col] : 0.f;
#pragma unroll
    for (int m = 0; m < 4; ++m) {
      const int row0 = rowBase + wr * 64 + m * 16 + fg * 4;
      float y[4];
#pragma unroll
      for (int j = 0; j < 4; ++j) {
        float val = acc[m][n][j] + bc;
        if (rH) val += h2f(rH[(long)(row0 + j) * ldc + col]);
        if (act) val = val > 0.f ? val : 0.01f * val;
        y[j] = val;
        if (oF) oF[(long)(row0 + j) * ldc + col] = val;
        if (oH) oH[(long)(row0 + j) * ldc + col] = f2h(val);
      }
      if (oT) {  // transposed fp16 store: 4 consecutive rows -> one 8B store
        uint2 pk;
        pk.x = (uint32_t)f2h(y[0]) | ((uint32_t)f2h(y[1]) << 16);
        pk.y = (uint32_t)f2h(y[2]) | ((uint32_t)f2h(y[3]) << 16);
        *(uint2*)&oT[(long)col * ldt + row0] = pk;
      }
    }
  }
}

// ---------------- row softmax: fp16 [rows][2048] -> fp16 probs, IN-PLACE (R4-proven) ----------------
__global__ __launch_bounds__(256) void softmax_kernel(u16* __restrict__ buf) {
  __shared__ float red[16];
  const long base = (long)blockIdx.x * 2048;
  const int t = threadIdx.x, lane = t & 63, wv = t >> 6;
  const uint4 a = *(const uint4*)&buf[base + t * 8];   // 8 fp16
  float v[8] = {h2f((u16)(a.x & 0xFFFF)), h2f((u16)(a.x >> 16)),
                h2f((u16)(a.y & 0xFFFF)), h2f((u16)(a.y >> 16)),
                h2f((u16)(a.z & 0xFFFF)), h2f((u16)(a.z >> 16)),
                h2f((u16)(a.w & 0xFFFF)), h2f((u16)(a.w >> 16))};
  float mx = v[0];
#pragma unroll
  for (int i = 1; i < 8; ++i) mx = fmaxf(mx, v[i]);
#pragma unroll
  for (int o = 32; o; o >>= 1) mx = fmaxf(mx, __shfl_xor(mx, o));
  if (lane == 0) red[wv] = mx;
  __syncthreads();
  mx = fmaxf(fmaxf(red[0], red[1]), fmaxf(red[2], red[3]));
  float s = 0.f;
#pragma unroll
  for (int i = 0; i < 8; ++i) { v[i] = __expf(v[i] - mx); s += v[i]; }
#pragma unroll
  for (int o = 32; o; o >>= 1) s += __shfl_xor(s, o);
  if (lane == 0) red[8 + wv] = s;
  __syncthreads();   // orders all reads before the in-place writes
  const float inv = 1.f / (red[8] + red[9] + red[10] + red[11]);
  uint4 o4;
  o4.x = (uint32_t)f2h(v[0] * inv) | ((uint32_t)f2h(v[1] * inv) << 16);
  o4.y = (uint32_t)f2h(v[2] * inv) | ((uint32_t)f2h(v[3] * inv) << 16);
  o4.z = (uint32_t)f2h(v[4] * inv) | ((uint32_t)f2h(v[5] * inv) << 16);
  o4.w = (uint32_t)f2h(v[6] * inv) | ((uint32_t)f2h(v[7] * inv) << 16);
  *(uint4*)&buf[base + t * 8] = o4;
}

// ---------------- LayerNorm: fp32 OR fp16 input, optional fp32 residual ----------------
template <int W>
__global__ __launch_bounds__(256) void ln_kernel(
    const float* __restrict__ inF, const u16* __restrict__ inH, const float* __restrict__ resF,
    const float* __restrict__ gam, const float* __restrict__ bet,
    float* __restrict__ outF, u16* __restrict__ outH)
{
  constexpr int NV = W / 1024;
  __shared__ float red[16];
  const long base = (long)blockIdx.x * W;
  const int t = threadIdx.x, lane = t & 63, wv = t >> 6;
  float v[NV * 4];
  float s = 0.f, ss = 0.f;
#pragma unroll
  for (int c = 0; c < NV; ++c) {
    const int idx = (t + c * 256) * 4;
    float4 a;
    if (inF) a = *(const float4*)&inF[base + idx];
    else {
      const uint2 r = *(const uint2*)&inH[base + idx];
      a.x = h2f((u16)(r.x & 0xFFFF)); a.y = h2f((u16)(r.x >> 16));
      a.z = h2f((u16)(r.y & 0xFFFF)); a.w = h2f((u16)(r.y >> 16));
    }
    if (resF) {
      const float4 r4 = *(const float4*)&resF[base + idx];
      a.x += r4.x; a.y += r4.y; a.z += r4.z; a.w += r4.w;
    }
    v[c * 4 + 0] = a.x; v[c * 4 + 1] = a.y; v[c * 4 + 2] = a.z; v[c * 4 + 3] = a.w;
    s += a.x + a.y + a.z + a.w;
    ss += a.x * a.x + a.y * a.y + a.z * a.z + a.w * a.w;
  }
#pragma unroll
  for (int o = 32; o; o >>= 1) { s += __shfl_xor(s, o); ss += __shfl_xor(ss, o); }
  if (lane == 0) { red[wv] = s; red[8 + wv] = ss; }
  __syncthreads();
  s = red[0] + red[1] + red[2] + red[3];
  ss = red[8] + red[9] + red[10] + red[11];
  const float mean = s * (1.f / W);
  const float rstd = rsqrtf(ss * (1.f / W) - mean * mean + 1e-5f);
#pragma unroll
  for (int c = 0; c < NV; ++c) {
    const int idx = (t + c * 256) * 4;
    const float4 g4 = *(const float4*)&gam[idx];
    const float4 b4 = *(const float4*)&bet[idx];
    const float y0 = (v[c * 4 + 0] - mean) * rstd * g4.x + b4.x;
    const float y1 = (v[c * 4 + 1] - mean) * rstd * g4.y + b4.y;
    const float y2 = (v[c * 4 + 2] - mean) * rstd * g4.z + b4.z;
    const float y3 = (v[c * 4 + 3] - mean) * rstd * g4.w + b4.w;
    if (outF) { float4 o4 = {y0, y1, y2, y3}; *(float4*)&outF[base + idx] = o4; }
    if (outH) {
      uint2 p;
      p.x = (uint32_t)f2h(y0) | ((uint32_t)f2h(y1) << 16);
      p.y = (uint32_t)f2h(y2) | ((uint32_t)f2h(y3) << 16);
      *(uint2*)&outH[base + idx] = p;
    }
  }
}

// ============================== host ==============================
extern "C" void kernel_launch(void* const* d_in, const int* in_sizes, int n_in,
                              void* d_out, int out_size, void* d_ws, size_t ws_size,
                              hipStream_t stream) {
  const float* x   = (const float*)d_in[0];
  const float* wq  = (const float*)d_in[1];
  const float* bq  = (const float*)d_in[2];
  const float* wk  = (const float*)d_in[3];
  const float* bk  = (const float*)d_in[4];
  const float* wv  = (const float*)d_in[5];
  const float* bv  = (const float*)d_in[6];
  const float* w0  = (const float*)d_in[7];
  const float* b0  = (const float*)d_in[8];
  const float* w1  = (const float*)d_in[9];
  const float* b1  = (const float*)d_in[10];
  const float* lng = (const float*)d_in[11];
  const float* lnb = (const float*)d_in[12];
  const float* w2  = (const float*)d_in[13];
  const float* b2  = (const float*)d_in[14];
  const float* n1g = (const float*)d_in[15];
  const float* n1b = (const float*)d_in[16];
  const float* n2g = (const float*)d_in[17];
  const float* n2b = (const float*)d_in[18];
  float* out = (float*)d_out;

  const size_t NEED = 251658240u;  // 240 MiB — proven to fit (R2/R4)
  if (ws_size < NEED) {
    int k = (int)(ws_size >> 25); if (k > 60) k = 60;
    const float sentinel = ldexpf(1.0f, k + 4);
    fill_kernel<<<dim3((out_size + 255) / 256), dim3(256), 0, stream>>>(out, sentinel, out_size);
    return;
  }
  char* ws = (char*)d_ws;
  // ---- 240 MiB overlay (liveness re-audited for no-split pipeline) ----
  u16* xb    = (u16*)(ws);                    // [0..32)   x fp16; dead after QKV
  u16* sc    = (u16*)(ws);                    // [0..64)   fp16 scores -> probs in-place; dead after PV
  u16* hb    = (u16*)(ws);                    // [0..64)   LN(h) fp16 (step 9)
  u16* qb    = (u16*)(ws + 67108864);         // [64..96)  dead after scores
  u16* attnb = qb;                            // [64..96)  (step 5); dead after LN1
  u16* kb    = (u16*)(ws + 100663296);        // [96..128) dead after scores
  u16* tb    = kb;                            // [96..128) (step 6); dead after w0
  u16* vT    = (u16*)(ws + 134217728);        // [128..160) dead after PV
  u16* eb    = vT;                            // [128..160) (step 7); live through step 10 (residual)
  u16* hraw  = (u16*)(ws + 167772160);        // [160..224) (step 8); dead after LN2
  float* uF  = (float*)(ws + 67108864);       // [64..128) fp32 (step 10; attnb+tb dead)
  u16* wqT   = (u16*)(ws + 234881024);        // [224..240) weights fp16
  u16* wkT   = (u16*)(ws + 236978176);
  u16* wvT   = (u16*)(ws + 239075328);
  u16* w0T   = (u16*)(ws + 241172480);
  u16* w1T   = (u16*)(ws + 243269632);
  u16* w2T   = (u16*)(ws + 247463936);

  const dim3 b256(256);
  const dim3 tblk(32, 8);

  // 1) convert x -> fp16; transpose-convert weights to [out][in] fp16
  cvt_kernel<<<dim3(8192), b256, 0, stream>>>(x, xb);
  transpose_kernel<<<dim3(32, 32), tblk, 0, stream>>>(wq, wqT, 1024, 1024);
  transpose_kernel<<<dim3(32, 32), tblk, 0, stream>>>(wk, wkT, 1024, 1024);
  transpose_kernel<<<dim3(32, 32), tblk, 0, stream>>>(wv, wvT, 1024, 1024);
  transpose_kernel<<<dim3(32, 32), tblk, 0, stream>>>(w0, w0T, 1024, 1024);
  transpose_kernel<<<dim3(64, 32), tblk, 0, stream>>>(w1, w1T, 1024, 2048);
  transpose_kernel<<<dim3(32, 64), tblk, 0, stream>>>(w2, w2T, 2048, 1024);

  // 2) q, k fp16; v fp16 transposed -> vT[1024][16384]
  gemm_f16<<<dim3(8, 128, 1), b256, 0, stream>>>(xb, wqT, nullptr, qb, nullptr, bq, nullptr,
      0, 1024, 1024, 1024, 1024, 0, 0, 0, 0, 0);
  gemm_f16<<<dim3(8, 128, 1), b256, 0, stream>>>(xb, wkT, nullptr, kb, nullptr, bk, nullptr,
      0, 1024, 1024, 1024, 1024, 0, 0, 0, 0, 0);
  gemm_f16<<<dim3(8, 128, 1), b256, 0, stream>>>(xb, wvT, nullptr, nullptr, vT, bv, nullptr,
      0, 1024, 1024, 1024, 1024, 16384, 0, 0, 0, 0);

  // 3) scores[b] = q_b @ k_b^T -> fp16 (fp32 accum)
  gemm_f16<<<dim3(16, 16, 8), b256, 0, stream>>>(qb, kb, nullptr, sc, nullptr, nullptr, nullptr,
      0, 1024, 1024, 1024, 2048, 0, 2097152, 2097152, 4194304, 0);

  // 4) softmax rows (fp16 -> fp16 probs, in-place)
  softmax_kernel<<<dim3(16384), b256, 0, stream>>>(sc);

  // 5) attn[b] = probs_b @ v_b -> fp16 into attnb (qb region, dead)
  gemm_f16<<<dim3(8, 16, 8), b256, 0, stream>>>(sc, vT, nullptr, attnb, nullptr, nullptr, nullptr,
      0, 2048, 2048, 16384, 1024, 0, 4194304, 2048, 2097152, 0);

  // 6) tb = LN(x + attn; n1) -> fp16 (kb region, dead)
  ln_kernel<1024><<<dim3(16384), b256, 0, stream>>>(nullptr, attnb, x, n1g, n1b, nullptr, tb);

  // 7) eb = tb @ w0 + b0 -> fp16 (vT region, dead)
  gemm_f16<<<dim3(8, 128, 1), b256, 0, stream>>>(tb, w0T, nullptr, eb, nullptr, b0, nullptr,
      0, 1024, 1024, 1024, 1024, 0, 0, 0, 0, 0);

  // 8) hraw = leaky(eb @ w1 + b1) -> fp16 [160..224)
  gemm_f16<<<dim3(16, 128, 1), b256, 0, stream>>>(eb, w1T, nullptr, hraw, nullptr, b1, nullptr,
      1, 1024, 1024, 1024, 2048, 0, 0, 0, 0, 0);

  // 9) hb = LN(hraw; ln) -> fp16 (sc region, dead)
  ln_kernel<2048><<<dim3(16384), b256, 0, stream>>>(nullptr, hraw, nullptr, lng, lnb, nullptr, hb);

  // 10) uF = leaky(hb @ w2 + b2 + eb) -> fp32 (attnb+tb region, dead)
  gemm_f16<<<dim3(8, 128, 1), b256, 0, stream>>>(hb, w2T, uF, nullptr, nullptr, b2, eb,
      1, 2048, 2048, 2048, 1024, 0, 0, 0, 0, 0);

  // 11) out = LN(uF; n2) fp32
  ln_kernel<1024><<<dim3(16384), b256, 0, stream>>>(uF, nullptr, nullptr, n2g, n2b, out, nullptr);
}

// Round 8
// 903.987 us; speedup vs baseline: 1.2760x; 1.1380x over previous
//
#include <hip/hip_runtime.h>
#include <cstdint>
#include <cmath>

typedef unsigned short u16;
typedef __attribute__((ext_vector_type(4))) float f32x4;
typedef __attribute__((ext_vector_type(8))) _Float16 f16x8;

#define GPTR(p) ((__attribute__((address_space(1))) void*)(uintptr_t)(p))
#define LPTR(p) ((__attribute__((address_space(3))) void*)(uint32_t)(uintptr_t)(p))

__device__ __forceinline__ u16 f2h(float f) {
  const _Float16 h = (_Float16)f;   // RNE
  return __builtin_bit_cast(u16, h);
}
__device__ __forceinline__ float h2f(u16 v) {
  return (float)__builtin_bit_cast(_Float16, v);
}

// ---------------- diagnostic fill (ws too small; exponent-coded sentinel) ----------------
__global__ __launch_bounds__(256) void fill_kernel(float* __restrict__ p, float v, long n) {
  const long i = (long)blockIdx.x * 256 + threadIdx.x;
  if (i < n) p[i] = v;
}

// ---------------- fp32 -> fp16 convert (8 elems/thread) ----------------
__global__ __launch_bounds__(256) void cvt_kernel(const float* __restrict__ src, u16* __restrict__ dst) {
  const long i = ((long)blockIdx.x * 256 + threadIdx.x) * 8;
  const float4 a = *(const float4*)&src[i];
  const float4 b = *(const float4*)&src[i + 4];
  uint4 o;
  o.x = (uint32_t)f2h(a.x) | ((uint32_t)f2h(a.y) << 16);
  o.y = (uint32_t)f2h(a.z) | ((uint32_t)f2h(a.w) << 16);
  o.z = (uint32_t)f2h(b.x) | ((uint32_t)f2h(b.y) << 16);
  o.w = (uint32_t)f2h(b.z) | ((uint32_t)f2h(b.w) << 16);
  *(uint4*)&dst[i] = o;
}

// ---------------- fp32 [R][C] -> fp16 [C][R] transpose-convert ----------------
__global__ void transpose_kernel(const float* __restrict__ src, u16* __restrict__ dst, int R, int C) {
  __shared__ float tile[32][33];
  const int bx = blockIdx.x * 32, by = blockIdx.y * 32;
  const int tx = threadIdx.x, ty = threadIdx.y;  // block (32,8)
#pragma unroll
  for (int i = 0; i < 32; i += 8) tile[ty + i][tx] = src[(long)(by + ty + i) * C + bx + tx];
  __syncthreads();
#pragma unroll
  for (int i = 0; i < 32; i += 8) dst[(long)(bx + ty + i) * R + by + tx] = f2h(tile[tx][ty + i]);
}

// =================================================================================
// fp16 MFMA GEMM, 256x128 tile, 8 waves (4M x 2N), BK=64, TRIPLE-buffered LDS,
// counted-vmcnt pipeline (T3/T4), XOR-swizzled LDS (T2), setprio MFMA cluster (T5).
// C = A @ Bt^T (+bias) (+resH) (leaky) -> fp32 / fp16 / fp16-transposed.
//
// LDS map (u16 idx): A buf b (b=0..2): [b*16384 .. +16384)   (256 rows x 64 f16)
//                    B buf b:          [49152 + b*8192 .. +8192) (128 rows x 64)
// Total 144 KiB. Triple buffer: STAGE(t+2) targets the buffer consumed at iter
// t-1 — a full iteration of WAR distance (vs 0 in the double-buffered R7, which
// raced intermittently under graph replay).
// Swizzle: 16B chunk j at row r lives at chunk (j ^ (r&7)); staging pre-swizzles
// the GLOBAL source (linear gload_lds dest), reads XOR the chunk index. (rule #21)
// =================================================================================
__global__ __launch_bounds__(512, 2) void gemm256(
    const u16* __restrict__ A, const u16* __restrict__ Bt,
    float* __restrict__ outF, u16* __restrict__ outH, u16* __restrict__ outT,
    const float* __restrict__ bias, const u16* __restrict__ resH,
    int act,
    int K, int lda, int ldb, int ldc, int ldt,
    long strA, long strB, long strC, long strT)
{
  __shared__ alignas(16) u16 lds[73728];   // 144 KiB

  const int tid = threadIdx.x;
  const int lane = tid & 63;
  const int wid = tid >> 6;
  const int wr = wid >> 1, wc = wid & 1;   // 4 x 2 waves
  const int fr = lane & 15, fg = lane >> 4;

  const int z = blockIdx.z;
  const int rowBase = blockIdx.y * 256;
  const int colBase = blockIdx.x * 128;

  const u16* Ab = A + (long)z * strA;
  const u16* Bb = Bt + (long)z * strB;

  // staging geometry: thread t handles chunk c = i*512 + tid; row = c>>3, chunk jp = c&7.
  // source chunk = jp ^ (row&7)  (involution; row&7 == (tid>>3)&7 since i*64 ≡ 0 mod 8)
  const int sr = tid >> 3;                    // base row 0..63 (+i*64)
  const int jsrc = (tid & 7) ^ (sr & 7);      // pre-swizzled source chunk
  const u16* gA = Ab + (long)(rowBase + sr) * lda + jsrc * 8;
  const u16* gB = Bb + (long)(colBase + sr) * ldb + jsrc * 8;
  u16* lA = &lds[tid * 8];
  u16* lB = &lds[49152 + tid * 8];
  const int nk = K >> 6;

  f32x4 acc[4][4];
#pragma unroll
  for (int m = 0; m < 4; ++m)
#pragma unroll
    for (int n = 0; n < 4; ++n) acc[m][n] = (f32x4){0.f, 0.f, 0.f, 0.f};

#define STAGE(kt, b)                                                                          \
  do {                                                                                        \
    const long ko = (long)(kt) * 64;                                                          \
    _Pragma("unroll")                                                                         \
    for (int i = 0; i < 4; ++i)                                                               \
      __builtin_amdgcn_global_load_lds(GPTR(gA + ko + (long)i * 64 * lda),                    \
                                       LPTR(lA + (b) * 16384 + i * 4096), 16, 0, 0);          \
    _Pragma("unroll")                                                                         \
    for (int i = 0; i < 2; ++i)                                                               \
      __builtin_amdgcn_global_load_lds(GPTR(gB + ko + (long)i * 64 * ldb),                    \
                                       LPTR(lB + (b) * 8192 + i * 4096), 16, 0, 0);           \
  } while (0)

  STAGE(0, 0);
  STAGE(1, 1);

  int rb = 0;                                // read-buffer index = t % 3
  for (int t = 0; t < nk; ++t) {
    // tile t resident (6 newest loads = tile t+1 may stay in flight)
    if (t + 1 < nk) asm volatile("s_waitcnt vmcnt(6)" ::: "memory");
    else            asm volatile("s_waitcnt vmcnt(0)" ::: "memory");
    __builtin_amdgcn_s_barrier();
    __builtin_amdgcn_sched_barrier(0);

    const int abase = rb * 16384;
    const int bbase = 49152 + rb * 8192;

    // read ALL frags of tile t (swizzled addresses; conflict-free by construction)
    f16x8 af[4][2], bf[4][2];
#pragma unroll
    for (int m = 0; m < 4; ++m)
#pragma unroll
      for (int kk = 0; kk < 2; ++kk) {
        const int jp = (kk * 4 + fg) ^ (fr & 7);
        af[m][kk] = *(const f16x8*)&lds[abase + (wr * 64 + m * 16 + fr) * 64 + jp * 8];
      }
#pragma unroll
    for (int n = 0; n < 4; ++n)
#pragma unroll
      for (int kk = 0; kk < 2; ++kk) {
        const int jp = (kk * 4 + fg) ^ (fr & 7);
        bf[n][kk] = *(const f16x8*)&lds[bbase + (wc * 64 + n * 16 + fr) * 64 + jp * 8];
      }
    // all waves done with ALL their LDS reads -> safe to overwrite buffer (t-1)%3
    asm volatile("s_waitcnt lgkmcnt(0)" ::: "memory");
    __builtin_amdgcn_s_barrier();
    __builtin_amdgcn_sched_barrier(0);
    if (t + 2 < nk) {
      const int wbuf = rb == 0 ? 2 : rb - 1;  // (t+2)%3 — consumed at iter t-1
      STAGE(t + 2, wbuf);
    }

    __builtin_amdgcn_s_setprio(1);
#pragma unroll
    for (int m = 0; m < 4; ++m)
#pragma unroll
      for (int n = 0; n < 4; ++n) {
        acc[m][n] = __builtin_amdgcn_mfma_f32_16x16x32_f16(af[m][0], bf[n][0], acc[m][n], 0, 0, 0);
        acc[m][n] = __builtin_amdgcn_mfma_f32_16x16x32_f16(af[m][1], bf[n][1], acc[m][n], 0, 0, 0);
      }
    __builtin_amdgcn_s_setprio(0);

    rb = rb == 2 ? 0 : rb + 1;
  }
#undef STAGE

  // -------- epilogue (R4-R7-proven math; wave map wr in [0,4), wc in [0,2)) --------
  float* oF = outF ? outF + (long)z * strC : nullptr;
  u16* oH = outH ? outH + (long)z * strC : nullptr;
  u16* oT = outT ? outT + (long)z * strT : nullptr;
  const u16* rH = resH ? resH + (long)z * strC : nullptr;

#pragma unroll
  for (int n = 0; n < 4; ++n) {
    const int col = colBase + wc * 64 + n * 16 + fr;
    const float bc = bias ? bias[col] : 0.f;
#pragma unroll
    for (int m = 0; m < 4; ++m) {
      const int row0 = rowBase + wr * 64 + m * 16 + fg * 4;
      float y[4];
#pragma unroll
      for (int j = 0; j < 4; ++j) {
        float val = acc[m][n][j] + bc;
        if (rH) val += h2f(rH[(long)(row0 + j) * ldc + col]);
        if (act) val = val > 0.f ? val : 0.01f * val;
        y[j] = val;
        if (oF) oF[(long)(row0 + j) * ldc + col] = val;
        if (oH) oH[(long)(row0 + j) * ldc + col] = f2h(val);
      }
      if (oT) {  // transposed fp16 store: 4 consecutive rows -> one 8B store
        uint2 pk;
        pk.x = (uint32_t)f2h(y[0]) | ((uint32_t)f2h(y[1]) << 16);
        pk.y = (uint32_t)f2h(y[2]) | ((uint32_t)f2h(y[3]) << 16);
        *(uint2*)&oT[(long)col * ldt + row0] = pk;
      }
    }
  }
}

// ---------------- row softmax: fp16 [rows][2048] -> fp16 probs, IN-PLACE (proven) ----------------
__global__ __launch_bounds__(256) void softmax_kernel(u16* __restrict__ buf) {
  __shared__ float red[16];
  const long base = (long)blockIdx.x * 2048;
  const int t = threadIdx.x, lane = t & 63, wv = t >> 6;
  const uint4 a = *(const uint4*)&buf[base + t * 8];   // 8 fp16
  float v[8] = {h2f((u16)(a.x & 0xFFFF)), h2f((u16)(a.x >> 16)),
                h2f((u16)(a.y & 0xFFFF)), h2f((u16)(a.y >> 16)),
                h2f((u16)(a.z & 0xFFFF)), h2f((u16)(a.z >> 16)),
                h2f((u16)(a.w & 0xFFFF)), h2f((u16)(a.w >> 16))};
  float mx = v[0];
#pragma unroll
  for (int i = 1; i < 8; ++i) mx = fmaxf(mx, v[i]);
#pragma unroll
  for (int o = 32; o; o >>= 1) mx = fmaxf(mx, __shfl_xor(mx, o));
  if (lane == 0) red[wv] = mx;
  __syncthreads();
  mx = fmaxf(fmaxf(red[0], red[1]), fmaxf(red[2], red[3]));
  float s = 0.f;
#pragma unroll
  for (int i = 0; i < 8; ++i) { v[i] = __expf(v[i] - mx); s += v[i]; }
#pragma unroll
  for (int o = 32; o; o >>= 1) s += __shfl_xor(s, o);
  if (lane == 0) red[8 + wv] = s;
  __syncthreads();   // orders all reads before the in-place writes
  const float inv = 1.f / (red[8] + red[9] + red[10] + red[11]);
  uint4 o4;
  o4.x = (uint32_t)f2h(v[0] * inv) | ((uint32_t)f2h(v[1] * inv) << 16);
  o4.y = (uint32_t)f2h(v[2] * inv) | ((uint32_t)f2h(v[3] * inv) << 16);
  o4.z = (uint32_t)f2h(v[4] * inv) | ((uint32_t)f2h(v[5] * inv) << 16);
  o4.w = (uint32_t)f2h(v[6] * inv) | ((uint32_t)f2h(v[7] * inv) << 16);
  *(uint4*)&buf[base + t * 8] = o4;
}

// ---------------- LayerNorm: fp32 OR fp16 input, optional fp32 residual ----------------
template <int W>
__global__ __launch_bounds__(256) void ln_kernel(
    const float* __restrict__ inF, const u16* __restrict__ inH, const float* __restrict__ resF,
    const float* __restrict__ gam, const float* __restrict__ bet,
    float* __restrict__ outF, u16* __restrict__ outH)
{
  constexpr int NV = W / 1024;
  __shared__ float red[16];
  const long base = (long)blockIdx.x * W;
  const int t = threadIdx.x, lane = t & 63, wv = t >> 6;
  float v[NV * 4];
  float s = 0.f, ss = 0.f;
#pragma unroll
  for (int c = 0; c < NV; ++c) {
    const int idx = (t + c * 256) * 4;
    float4 a;
    if (inF) a = *(const float4*)&inF[base + idx];
    else {
      const uint2 r = *(const uint2*)&inH[base + idx];
      a.x = h2f((u16)(r.x & 0xFFFF)); a.y = h2f((u16)(r.x >> 16));
      a.z = h2f((u16)(r.y & 0xFFFF)); a.w = h2f((u16)(r.y >> 16));
    }
    if (resF) {
      const float4 r4 = *(const float4*)&resF[base + idx];
      a.x += r4.x; a.y += r4.y; a.z += r4.z; a.w += r4.w;
    }
    v[c * 4 + 0] = a.x; v[c * 4 + 1] = a.y; v[c * 4 + 2] = a.z; v[c * 4 + 3] = a.w;
    s += a.x + a.y + a.z + a.w;
    ss += a.x * a.x + a.y * a.y + a.z * a.z + a.w * a.w;
  }
#pragma unroll
  for (int o = 32; o; o >>= 1) { s += __shfl_xor(s, o); ss += __shfl_xor(ss, o); }
  if (lane == 0) { red[wv] = s; red[8 + wv] = ss; }
  __syncthreads();
  s = red[0] + red[1] + red[2] + red[3];
  ss = red[8] + red[9] + red[10] + red[11];
  const float mean = s * (1.f / W);
  const float rstd = rsqrtf(ss * (1.f / W) - mean * mean + 1e-5f);
#pragma unroll
  for (int c = 0; c < NV; ++c) {
    const int idx = (t + c * 256) * 4;
    const float4 g4 = *(const float4*)&gam[idx];
    const float4 b4 = *(const float4*)&bet[idx];
    const float y0 = (v[c * 4 + 0] - mean) * rstd * g4.x + b4.x;
    const float y1 = (v[c * 4 + 1] - mean) * rstd * g4.y + b4.y;
    const float y2 = (v[c * 4 + 2] - mean) * rstd * g4.z + b4.z;
    const float y3 = (v[c * 4 + 3] - mean) * rstd * g4.w + b4.w;
    if (outF) { float4 o4 = {y0, y1, y2, y3}; *(float4*)&outF[base + idx] = o4; }
    if (outH) {
      uint2 p;
      p.x = (uint32_t)f2h(y0) | ((uint32_t)f2h(y1) << 16);
      p.y = (uint32_t)f2h(y2) | ((uint32_t)f2h(y3) << 16);
      *(uint2*)&outH[base + idx] = p;
    }
  }
}

// ============================== host ==============================
extern "C" void kernel_launch(void* const* d_in, const int* in_sizes, int n_in,
                              void* d_out, int out_size, void* d_ws, size_t ws_size,
                              hipStream_t stream) {
  const float* x   = (const float*)d_in[0];
  const float* wq  = (const float*)d_in[1];
  const float* bq  = (const float*)d_in[2];
  const float* wk  = (const float*)d_in[3];
  const float* bk  = (const float*)d_in[4];
  const float* wv  = (const float*)d_in[5];
  const float* bv  = (const float*)d_in[6];
  const float* w0  = (const float*)d_in[7];
  const float* b0  = (const float*)d_in[8];
  const float* w1  = (const float*)d_in[9];
  const float* b1  = (const float*)d_in[10];
  const float* lng = (const float*)d_in[11];
  const float* lnb = (const float*)d_in[12];
  const float* w2  = (const float*)d_in[13];
  const float* b2  = (const float*)d_in[14];
  const float* n1g = (const float*)d_in[15];
  const float* n1b = (const float*)d_in[16];
  const float* n2g = (const float*)d_in[17];
  const float* n2b = (const float*)d_in[18];
  float* out = (float*)d_out;

  const size_t NEED = 251658240u;  // 240 MiB — proven to fit (R2/R4/R5)
  if (ws_size < NEED) {
    int k = (int)(ws_size >> 25); if (k > 60) k = 60;
    const float sentinel = ldexpf(1.0f, k + 4);
    fill_kernel<<<dim3((out_size + 255) / 256), dim3(256), 0, stream>>>(out, sentinel, out_size);
    return;
  }
  char* ws = (char*)d_ws;
  // ---- 240 MiB overlay (R5-proven liveness) ----
  u16* xb    = (u16*)(ws);                    // [0..32)   x fp16; dead after QKV
  u16* sc    = (u16*)(ws);                    // [0..64)   fp16 scores -> probs in-place; dead after PV
  u16* hb    = (u16*)(ws);                    // [0..64)   LN(h) fp16 (step 9)
  u16* qb    = (u16*)(ws + 67108864);         // [64..96)  dead after scores
  u16* attnb = qb;                            // [64..96)  (step 5); dead after LN1
  u16* kb    = (u16*)(ws + 100663296);        // [96..128) dead after scores
  u16* tb    = kb;                            // [96..128) (step 6); dead after w0
  u16* vT    = (u16*)(ws + 134217728);        // [128..160) dead after PV
  u16* eb    = vT;                            // [128..160) (step 7); live through step 10 (residual)
  u16* hraw  = (u16*)(ws + 167772160);        // [160..224) (step 8); dead after LN2
  float* uF  = (float*)(ws + 67108864);       // [64..128) fp32 (step 10; attnb+tb dead)
  u16* wqT   = (u16*)(ws + 234881024);        // [224..240) weights fp16
  u16* wkT   = (u16*)(ws + 236978176);
  u16* wvT   = (u16*)(ws + 239075328);
  u16* w0T   = (u16*)(ws + 241172480);
  u16* w1T   = (u16*)(ws + 243269632);
  u16* w2T   = (u16*)(ws + 247463936);

  const dim3 b256(256);
  const dim3 b512(512);
  const dim3 tblk(32, 8);

  // 1) convert x -> fp16; transpose-convert weights to [out][in] fp16
  cvt_kernel<<<dim3(8192), b256, 0, stream>>>(x, xb);
  transpose_kernel<<<dim3(32, 32), tblk, 0, stream>>>(wq, wqT, 1024, 1024);
  transpose_kernel<<<dim3(32, 32), tblk, 0, stream>>>(wk, wkT, 1024, 1024);
  transpose_kernel<<<dim3(32, 32), tblk, 0, stream>>>(wv, wvT, 1024, 1024);
  transpose_kernel<<<dim3(32, 32), tblk, 0, stream>>>(w0, w0T, 1024, 1024);
  transpose_kernel<<<dim3(64, 32), tblk, 0, stream>>>(w1, w1T, 1024, 2048);
  transpose_kernel<<<dim3(32, 64), tblk, 0, stream>>>(w2, w2T, 2048, 1024);

  // 2) q, k fp16; v fp16 transposed -> vT[1024][16384]
  gemm256<<<dim3(8, 64, 1), b512, 0, stream>>>(xb, wqT, nullptr, qb, nullptr, bq, nullptr,
      0, 1024, 1024, 1024, 1024, 0, 0, 0, 0, 0);
  gemm256<<<dim3(8, 64, 1), b512, 0, stream>>>(xb, wkT, nullptr, kb, nullptr, bk, nullptr,
      0, 1024, 1024, 1024, 1024, 0, 0, 0, 0, 0);
  gemm256<<<dim3(8, 64, 1), b512, 0, stream>>>(xb, wvT, nullptr, nullptr, vT, bv, nullptr,
      0, 1024, 1024, 1024, 1024, 16384, 0, 0, 0, 0);

  // 3) scores[b] = q_b @ k_b^T -> fp16 (fp32 accum)
  gemm256<<<dim3(16, 8, 8), b512, 0, stream>>>(qb, kb, nullptr, sc, nullptr, nullptr, nullptr,
      0, 1024, 1024, 1024, 2048, 0, 2097152, 2097152, 4194304, 0);

  // 4) softmax rows (fp16 -> fp16 probs, in-place)
  softmax_kernel<<<dim3(16384), b256, 0, stream>>>(sc);

  // 5) attn[b] = probs_b @ v_b -> fp16 into attnb (qb region, dead)
  gemm256<<<dim3(8, 8, 8), b512, 0, stream>>>(sc, vT, nullptr, attnb, nullptr, nullptr, nullptr,
      0, 2048, 2048, 16384, 1024, 0, 4194304, 2048, 2097152, 0);

  // 6) tb = LN(x + attn; n1) -> fp16 (kb region, dead)
  ln_kernel<1024><<<dim3(16384), b256, 0, stream>>>(nullptr, attnb, x, n1g, n1b, nullptr, tb);

  // 7) eb = tb @ w0 + b0 -> fp16 (vT region, dead)
  gemm256<<<dim3(8, 64, 1), b512, 0, stream>>>(tb, w0T, nullptr, eb, nullptr, b0, nullptr,
      0, 1024, 1024, 1024, 1024, 0, 0, 0, 0, 0);

  // 8) hraw = leaky(eb @ w1 + b1) -> fp16 [160..224)
  gemm256<<<dim3(16, 64, 1), b512, 0, stream>>>(eb, w1T, nullptr, hraw, nullptr, b1, nullptr,
      1, 1024, 1024, 1024, 2048, 0, 0, 0, 0, 0);

  // 9) hb = LN(hraw; ln) -> fp16 (sc region, dead)
  ln_kernel<2048><<<dim3(16384), b256, 0, stream>>>(nullptr, hraw, nullptr, lng, lnb, nullptr, hb);

  // 10) uF = leaky(hb @ w2 + b2 + eb) -> fp32 (attnb+tb region, dead)
  gemm256<<<dim3(8, 64, 1), b512, 0, stream>>>(hb, w2T, uF, nullptr, nullptr, b2, eb,
      1, 2048, 2048, 2048, 1024, 0, 0, 0, 0, 0);

  // 11) out = LN(uF; n2) fp32
  ln_kernel<1024><<<dim3(16384), b256, 0, stream>>>(uF, nullptr, nullptr, n2g, n2b, out, nullptr);
}

// Round 11
// 866.448 us; speedup vs baseline: 1.3313x; 1.0433x over previous
//
#include <hip/hip_runtime.h>
#include <cstdint>
#include <cmath>

typedef unsigned short u16;
typedef __attribute__((ext_vector_type(4))) float f32x4;
typedef __attribute__((ext_vector_type(8))) _Float16 f16x8;

#define GPTR(p) ((__attribute__((address_space(1))) void*)(uintptr_t)(p))
#define LPTR(p) ((__attribute__((address_space(3))) void*)(uint32_t)(uintptr_t)(p))

__device__ __forceinline__ u16 f2h(float f) {
  const _Float16 h = (_Float16)f;   // RNE
  return __builtin_bit_cast(u16, h);
}
__device__ __forceinline__ float h2f(u16 v) {
  return (float)__builtin_bit_cast(_Float16, v);
}

// ---------------- diagnostic fill (ws too small; exponent-coded sentinel) ----------------
__global__ __launch_bounds__(256) void fill_kernel(float* __restrict__ p, float v, long n) {
  const long i = (long)blockIdx.x * 256 + threadIdx.x;
  if (i < n) p[i] = v;
}

// ---------------- fp32 -> fp16 convert (8 elems/thread) ----------------
__global__ __launch_bounds__(256) void cvt_kernel(const float* __restrict__ src, u16* __restrict__ dst) {
  const long i = ((long)blockIdx.x * 256 + threadIdx.x) * 8;
  const float4 a = *(const float4*)&src[i];
  const float4 b = *(const float4*)&src[i + 4];
  uint4 o;
  o.x = (uint32_t)f2h(a.x) | ((uint32_t)f2h(a.y) << 16);
  o.y = (uint32_t)f2h(a.z) | ((uint32_t)f2h(a.w) << 16);
  o.z = (uint32_t)f2h(b.x) | ((uint32_t)f2h(b.y) << 16);
  o.w = (uint32_t)f2h(b.z) | ((uint32_t)f2h(b.w) << 16);
  *(uint4*)&dst[i] = o;
}

// ---------------- fp32 [R][C] -> fp16 [C][R] transpose-convert ----------------
__global__ void transpose_kernel(const float* __restrict__ src, u16* __restrict__ dst, int R, int C) {
  __shared__ float tile[32][33];
  const int bx = blockIdx.x * 32, by = blockIdx.y * 32;
  const int tx = threadIdx.x, ty = threadIdx.y;  // block (32,8)
#pragma unroll
  for (int i = 0; i < 32; i += 8) tile[ty + i][tx] = src[(long)(by + ty + i) * C + bx + tx];
  __syncthreads();
#pragma unroll
  for (int i = 0; i < 32; i += 8) dst[(long)(bx + ty + i) * R + by + tx] = f2h(tile[tx][ty + i]);
}

// =================================================================================
// fp16 MFMA GEMM, 256x128 tile, 8 waves (4M x 2N), BK=64, TRIPLE-buffered LDS,
// SINGLE barrier per K-step (WAR safety from the 2-iteration triple-buffer
// distance + data-dependence lgkm waits), counted-vmcnt prefetch (T3/T4),
// XOR-swizzled LDS (T2, verified conflict-free in R8: SQ_LDS_BANK_CONFLICT=0),
// setprio (T5), XCD-grouped tile remap (T1: same-A-panel blocks -> same XCD L2).
// C = A @ Bt^T (+bias) (+resH) (leaky) -> fp32 / fp16 / fp16-transposed.
//
// LDS map (u16 idx): A buf b (b=0..2): [b*16384 .. +16384)   (256 rows x 64 f16)
//                    B buf b:          [49152 + b*8192 .. +8192) (128 rows x 64)
// Swizzle: 16B chunk j at row r lives at chunk (j ^ (r&7)); staging pre-swizzles
// the GLOBAL source (linear gload_lds dest), reads XOR the chunk index. (rule #21)
// =================================================================================
__global__ __launch_bounds__(512, 2) void gemm256(
    const u16* __restrict__ A, const u16* __restrict__ Bt,
    float* __restrict__ outF, u16* __restrict__ outH, u16* __restrict__ outT,
    const float* __restrict__ bias, const u16* __restrict__ resH,
    int act,
    int K, int lda, int ldb, int ldc, int ldt,
    long strA, long strB, long strC, long strT)
{
  __shared__ alignas(16) u16 lds[73728];   // 144 KiB

  const int tid = threadIdx.x;
  const int lane = tid & 63;
  const int wid = tid >> 6;
  const int wr = wid >> 1, wc = wid & 1;   // 4 x 2 waves
  const int fr = lane & 15, fg = lane >> 4;

  // ---- XCD-grouped tile remap: blocks sharing an A-panel (same y,z) -> one XCD.
  // HW dispatch index f -> XCD f%8 (round-robin heuristic). Decompose
  // f = a + 8*b + W*c (W = gy*gz panel groups, X = gx): panel w = a*(W/8)+b gets
  // all its X blocks at fixed a = fixed XCD. Bijective when W%8==0 (all our grids).
  int bx_ = blockIdx.x, by_ = blockIdx.y, bz_ = blockIdx.z;
  {
    const int X = gridDim.x, gy = gridDim.y;
    const int W = gy * gridDim.z;
    if ((W & 7) == 0) {
      const int f = blockIdx.x + X * (blockIdx.y + gy * blockIdx.z);
      const int a = f & 7, b8 = (f >> 3) % (W >> 3), c = f / W;
      const int w = a * (W >> 3) + b8;
      bx_ = c; by_ = w % gy; bz_ = w / gy;
    }
  }
  const int z = bz_;
  const int rowBase = by_ * 256;
  const int colBase = bx_ * 128;

  const u16* Ab = A + (long)z * strA;
  const u16* Bb = Bt + (long)z * strB;

  // staging geometry: thread t handles chunk c = i*512 + tid; row = c>>3, chunk jp = c&7.
  // source chunk = jp ^ (row&7)  (involution; row&7 == (tid>>3)&7 since i*64 ≡ 0 mod 8)
  const int sr = tid >> 3;                    // base row 0..63 (+i*64)
  const int jsrc = (tid & 7) ^ (sr & 7);      // pre-swizzled source chunk
  const u16* gA = Ab + (long)(rowBase + sr) * lda + jsrc * 8;
  const u16* gB = Bb + (long)(colBase + sr) * ldb + jsrc * 8;
  u16* lA = &lds[tid * 8];
  u16* lB = &lds[49152 + tid * 8];
  const int nk = K >> 6;

  f32x4 acc[4][4];
#pragma unroll
  for (int m = 0; m < 4; ++m)
#pragma unroll
    for (int n = 0; n < 4; ++n) acc[m][n] = (f32x4){0.f, 0.f, 0.f, 0.f};

#define STAGE(kt, b)                                                                          \
  do {                                                                                        \
    const long ko = (long)(kt) * 64;                                                          \
    _Pragma("unroll")                                                                         \
    for (int i = 0; i < 4; ++i)                                                               \
      __builtin_amdgcn_global_load_lds(GPTR(gA + ko + (long)i * 64 * lda),                    \
                                       LPTR(lA + (b) * 16384 + i * 4096), 16, 0, 0);          \
    _Pragma("unroll")                                                                         \
    for (int i = 0; i < 2; ++i)                                                               \
      __builtin_amdgcn_global_load_lds(GPTR(gB + ko + (long)i * 64 * ldb),                    \
                                       LPTR(lB + (b) * 8192 + i * 4096), 16, 0, 0);           \
  } while (0)

  STAGE(0, 0);
  STAGE(1, 1);

  int rb = 0;   // read buffer = t % 3
  int wb = 2;   // stage target = (t+2) % 3 — the buffer consumed at iter t-1
  for (int t = 0; t < nk; ++t) {
    // tile t resident (6 newest loads = tile t+1 may stay in flight)
    if (t + 1 < nk) asm volatile("s_waitcnt vmcnt(6)" ::: "memory");
    else            asm volatile("s_waitcnt vmcnt(0)" ::: "memory");
    __builtin_amdgcn_s_barrier();
    __builtin_amdgcn_sched_barrier(0);

    // prefetch tile t+2 early (in flight across the whole compute phase).
    // WAR-safe: wb's readers (iter t-1) consumed their data before entering
    // this iteration's barrier (MFMA source operands force the lgkm wait).
    if (t + 2 < nk) STAGE(t + 2, wb);

    const int abase = rb * 16384;
    const int bbase = 49152 + rb * 8192;

    __builtin_amdgcn_s_setprio(1);
    // frag reads + MFMAs, compiler-scheduled (fine-grained lgkmcnt interleave)
    f16x8 af[4][2], bf[4][2];
#pragma unroll
    for (int m = 0; m < 4; ++m)
#pragma unroll
      for (int kk = 0; kk < 2; ++kk) {
        const int jp = (kk * 4 + fg) ^ (fr & 7);
        af[m][kk] = *(const f16x8*)&lds[abase + (wr * 64 + m * 16 + fr) * 64 + jp * 8];
      }
#pragma unroll
    for (int n = 0; n < 4; ++n)
#pragma unroll
      for (int kk = 0; kk < 2; ++kk) {
        const int jp = (kk * 4 + fg) ^ (fr & 7);
        bf[n][kk] = *(const f16x8*)&lds[bbase + (wc * 64 + n * 16 + fr) * 64 + jp * 8];
      }
#pragma unroll
    for (int m = 0; m < 4; ++m)
#pragma unroll
      for (int n = 0; n < 4; ++n) {
        acc[m][n] = __builtin_amdgcn_mfma_f32_16x16x32_f16(af[m][0], bf[n][0], acc[m][n], 0, 0, 0);
        acc[m][n] = __builtin_amdgcn_mfma_f32_16x16x32_f16(af[m][1], bf[n][1], acc[m][n], 0, 0, 0);
      }
    __builtin_amdgcn_s_setprio(0);

    rb = rb == 2 ? 0 : rb + 1;
    wb = wb == 2 ? 0 : wb + 1;
  }
#undef STAGE

  // -------- epilogue (R4-R8-proven math; wave map wr in [0,4), wc in [0,2)) --------
  float* oF = outF ? outF + (long)z * strC : nullptr;
  u16* oH = outH ? outH + (long)z * strC : nullptr;
  u16* oT = outT ? outT + (long)z * strT : nullptr;
  const u16* rH = resH ? resH + (long)z * strC : nullptr;

#pragma unroll
  for (int n = 0; n < 4; ++n) {
    const int col = colBase + wc * 64 + n * 16 + fr;
    const float bc = bias ? bias[col] : 0.f;
#pragma unroll
    for (int m = 0; m < 4; ++m) {
      const int row0 = rowBase + wr * 64 + m * 16 + fg * 4;
      float y[4];
#pragma unroll
      for (int j = 0; j < 4; ++j) {
        float val = acc[m][n][j] + bc;
        if (rH) val += h2f(rH[(long)(row0 + j) * ldc + col]);
        if (act) val = val > 0.f ? val : 0.01f * val;
        y[j] = val;
        if (oF) oF[(long)(row0 + j) * ldc + col] = val;
        if (oH) oH[(long)(row0 + j) * ldc + col] = f2h(val);
      }
      if (oT) {  // transposed fp16 store: 4 consecutive rows -> one 8B store
        uint2 pk;
        pk.x = (uint32_t)f2h(y[0]) | ((uint32_t)f2h(y[1]) << 16);
        pk.y = (uint32_t)f2h(y[2]) | ((uint32_t)f2h(y[3]) << 16);
        *(uint2*)&oT[(long)col * ldt + row0] = pk;
      }
    }
  }
}

// ---------------- row softmax: fp16 [rows][2048] -> fp16 probs, IN-PLACE (proven) ----------------
__global__ __launch_bounds__(256) void softmax_kernel(u16* __restrict__ buf) {
  __shared__ float red[16];
  const long base = (long)blockIdx.x * 2048;
  const int t = threadIdx.x, lane = t & 63, wv = t >> 6;
  const uint4 a = *(const uint4*)&buf[base + t * 8];   // 8 fp16
  float v[8] = {h2f((u16)(a.x & 0xFFFF)), h2f((u16)(a.x >> 16)),
                h2f((u16)(a.y & 0xFFFF)), h2f((u16)(a.y >> 16)),
                h2f((u16)(a.z & 0xFFFF)), h2f((u16)(a.z >> 16)),
                h2f((u16)(a.w & 0xFFFF)), h2f((u16)(a.w >> 16))};
  float mx = v[0];
#pragma unroll
  for (int i = 1; i < 8; ++i) mx = fmaxf(mx, v[i]);
#pragma unroll
  for (int o = 32; o; o >>= 1) mx = fmaxf(mx, __shfl_xor(mx, o));
  if (lane == 0) red[wv] = mx;
  __syncthreads();
  mx = fmaxf(fmaxf(red[0], red[1]), fmaxf(red[2], red[3]));
  float s = 0.f;
#pragma unroll
  for (int i = 0; i < 8; ++i) { v[i] = __expf(v[i] - mx); s += v[i]; }
#pragma unroll
  for (int o = 32; o; o >>= 1) s += __shfl_xor(s, o);
  if (lane == 0) red[8 + wv] = s;
  __syncthreads();   // orders all reads before the in-place writes
  const float inv = 1.f / (red[8] + red[9] + red[10] + red[11]);
  uint4 o4;
  o4.x = (uint32_t)f2h(v[0] * inv) | ((uint32_t)f2h(v[1] * inv) << 16);
  o4.y = (uint32_t)f2h(v[2] * inv) | ((uint32_t)f2h(v[3] * inv) << 16);
  o4.z = (uint32_t)f2h(v[4] * inv) | ((uint32_t)f2h(v[5] * inv) << 16);
  o4.w = (uint32_t)f2h(v[6] * inv) | ((uint32_t)f2h(v[7] * inv) << 16);
  *(uint4*)&buf[base + t * 8] = o4;
}

// ---------------- LayerNorm: fp32 OR fp16 input, optional fp32 residual ----------------
template <int W>
__global__ __launch_bounds__(256) void ln_kernel(
    const float* __restrict__ inF, const u16* __restrict__ inH, const float* __restrict__ resF,
    const float* __restrict__ gam, const float* __restrict__ bet,
    float* __restrict__ outF, u16* __restrict__ outH)
{
  constexpr int NV = W / 1024;
  __shared__ float red[16];
  const long base = (long)blockIdx.x * W;
  const int t = threadIdx.x, lane = t & 63, wv = t >> 6;
  float v[NV * 4];
  float s = 0.f, ss = 0.f;
#pragma unroll
  for (int c = 0; c < NV; ++c) {
    const int idx = (t + c * 256) * 4;
    float4 a;
    if (inF) a = *(const float4*)&inF[base + idx];
    else {
      const uint2 r = *(const uint2*)&inH[base + idx];
      a.x = h2f((u16)(r.x & 0xFFFF)); a.y = h2f((u16)(r.x >> 16));
      a.z = h2f((u16)(r.y & 0xFFFF)); a.w = h2f((u16)(r.y >> 16));
    }
    if (resF) {
      const float4 r4 = *(const float4*)&resF[base + idx];
      a.x += r4.x; a.y += r4.y; a.z += r4.z; a.w += r4.w;
    }
    v[c * 4 + 0] = a.x; v[c * 4 + 1] = a.y; v[c * 4 + 2] = a.z; v[c * 4 + 3] = a.w;
    s += a.x + a.y + a.z + a.w;
    ss += a.x * a.x + a.y * a.y + a.z * a.z + a.w * a.w;
  }
#pragma unroll
  for (int o = 32; o; o >>= 1) { s += __shfl_xor(s, o); ss += __shfl_xor(ss, o); }
  if (lane == 0) { red[wv] = s; red[8 + wv] = ss; }
  __syncthreads();
  s = red[0] + red[1] + red[2] + red[3];
  ss = red[8] + red[9] + red[10] + red[11];
  const float mean = s * (1.f / W);
  const float rstd = rsqrtf(ss * (1.f / W) - mean * mean + 1e-5f);
#pragma unroll
  for (int c = 0; c < NV; ++c) {
    const int idx = (t + c * 256) * 4;
    const float4 g4 = *(const float4*)&gam[idx];
    const float4 b4 = *(const float4*)&bet[idx];
    const float y0 = (v[c * 4 + 0] - mean) * rstd * g4.x + b4.x;
    const float y1 = (v[c * 4 + 1] - mean) * rstd * g4.y + b4.y;
    const float y2 = (v[c * 4 + 2] - mean) * rstd * g4.z + b4.z;
    const float y3 = (v[c * 4 + 3] - mean) * rstd * g4.w + b4.w;
    if (outF) { float4 o4 = {y0, y1, y2, y3}; *(float4*)&outF[base + idx] = o4; }
    if (outH) {
      uint2 p;
      p.x = (uint32_t)f2h(y0) | ((uint32_t)f2h(y1) << 16);
      p.y = (uint32_t)f2h(y2) | ((uint32_t)f2h(y3) << 16);
      *(uint2*)&outH[base + idx] = p;
    }
  }
}

// ============================== host ==============================
extern "C" void kernel_launch(void* const* d_in, const int* in_sizes, int n_in,
                              void* d_out, int out_size, void* d_ws, size_t ws_size,
                              hipStream_t stream) {
  const float* x   = (const float*)d_in[0];
  const float* wq  = (const float*)d_in[1];
  const float* bq  = (const float*)d_in[2];
  const float* wk  = (const float*)d_in[3];
  const float* bk  = (const float*)d_in[4];
  const float* wv  = (const float*)d_in[5];
  const float* bv  = (const float*)d_in[6];
  const float* w0  = (const float*)d_in[7];
  const float* b0  = (const float*)d_in[8];
  const float* w1  = (const float*)d_in[9];
  const float* b1  = (const float*)d_in[10];
  const float* lng = (const float*)d_in[11];
  const float* lnb = (const float*)d_in[12];
  const float* w2  = (const float*)d_in[13];
  const float* b2  = (const float*)d_in[14];
  const float* n1g = (const float*)d_in[15];
  const float* n1b = (const float*)d_in[16];
  const float* n2g = (const float*)d_in[17];
  const float* n2b = (const float*)d_in[18];
  float* out = (float*)d_out;

  const size_t NEED = 251658240u;  // 240 MiB — proven to fit (R2/R4/R5/R8)
  if (ws_size < NEED) {
    int k = (int)(ws_size >> 25); if (k > 60) k = 60;
    const float sentinel = ldexpf(1.0f, k + 4);
    fill_kernel<<<dim3((out_size + 255) / 256), dim3(256), 0, stream>>>(out, sentinel, out_size);
    return;
  }
  char* ws = (char*)d_ws;
  // ---- 240 MiB overlay (R5/R8-proven liveness) ----
  u16* xb    = (u16*)(ws);                    // [0..32)   x fp16; dead after QKV
  u16* sc    = (u16*)(ws);                    // [0..64)   fp16 scores -> probs in-place; dead after PV
  u16* hb    = (u16*)(ws);                    // [0..64)   LN(h) fp16 (step 9)
  u16* qb    = (u16*)(ws + 67108864);         // [64..96)  dead after scores
  u16* attnb = qb;                            // [64..96)  (step 5); dead after LN1
  u16* kb    = (u16*)(ws + 100663296);        // [96..128) dead after scores
  u16* tb    = kb;                            // [96..128) (step 6); dead after w0
  u16* vT    = (u16*)(ws + 134217728);        // [128..160) dead after PV
  u16* eb    = vT;                            // [128..160) (step 7); live through step 10 (residual)
  u16* hraw  = (u16*)(ws + 167772160);        // [160..224) (step 8); dead after LN2
  float* uF  = (float*)(ws + 67108864);       // [64..128) fp32 (step 10; attnb+tb dead)
  u16* wqT   = (u16*)(ws + 234881024);        // [224..240) weights fp16
  u16* wkT   = (u16*)(ws + 236978176);
  u16* wvT   = (u16*)(ws + 239075328);
  u16* w0T   = (u16*)(ws + 241172480);
  u16* w1T   = (u16*)(ws + 243269632);
  u16* w2T   = (u16*)(ws + 247463936);

  const dim3 b256(256);
  const dim3 b512(512);
  const dim3 tblk(32, 8);

  // 1) convert x -> fp16; transpose-convert weights to [out][in] fp16
  cvt_kernel<<<dim3(8192), b256, 0, stream>>>(x, xb);
  transpose_kernel<<<dim3(32, 32), tblk, 0, stream>>>(wq, wqT, 1024, 1024);
  transpose_kernel<<<dim3(32, 32), tblk, 0, stream>>>(wk, wkT, 1024, 1024);
  transpose_kernel<<<dim3(32, 32), tblk, 0, stream>>>(wv, wvT, 1024, 1024);
  transpose_kernel<<<dim3(32, 32), tblk, 0, stream>>>(w0, w0T, 1024, 1024);
  transpose_kernel<<<dim3(64, 32), tblk, 0, stream>>>(w1, w1T, 1024, 2048);
  transpose_kernel<<<dim3(32, 64), tblk, 0, stream>>>(w2, w2T, 2048, 1024);

  // 2) q, k fp16; v fp16 transposed -> vT[1024][16384]
  gemm256<<<dim3(8, 64, 1), b512, 0, stream>>>(xb, wqT, nullptr, qb, nullptr, bq, nullptr,
      0, 1024, 1024, 1024, 1024, 0, 0, 0, 0, 0);
  gemm256<<<dim3(8, 64, 1), b512, 0, stream>>>(xb, wkT, nullptr, kb, nullptr, bk, nullptr,
      0, 1024, 1024, 1024, 1024, 0, 0, 0, 0, 0);
  gemm256<<<dim3(8, 64, 1), b512, 0, stream>>>(xb, wvT, nullptr, nullptr, vT, bv, nullptr,
      0, 1024, 1024, 1024, 1024, 16384, 0, 0, 0, 0);

  // 3) scores[b] = q_b @ k_b^T -> fp16 (fp32 accum)
  gemm256<<<dim3(16, 8, 8), b512, 0, stream>>>(qb, kb, nullptr, sc, nullptr, nullptr, nullptr,
      0, 1024, 1024, 1024, 2048, 0, 2097152, 2097152, 4194304, 0);

  // 4) softmax rows (fp16 -> fp16 probs, in-place)
  softmax_kernel<<<dim3(16384), b256, 0, stream>>>(sc);

  // 5) attn[b] = probs_b @ v_b -> fp16 into attnb (qb region, dead)
  gemm256<<<dim3(8, 8, 8), b512, 0, stream>>>(sc, vT, nullptr, attnb, nullptr, nullptr, nullptr,
      0, 2048, 2048, 16384, 1024, 0, 4194304, 2048, 2097152, 0);

  // 6) tb = LN(x + attn; n1) -> fp16 (kb region, dead)
  ln_kernel<1024><<<dim3(16384), b256, 0, stream>>>(nullptr, attnb, x, n1g, n1b, nullptr, tb);

  // 7) eb = tb @ w0 + b0 -> fp16 (vT region, dead)
  gemm256<<<dim3(8, 64, 1), b512, 0, stream>>>(tb, w0T, nullptr, eb, nullptr, b0, nullptr,
      0, 1024, 1024, 1024, 1024, 0, 0, 0, 0, 0);

  // 8) hraw = leaky(eb @ w1 + b1) -> fp16 [160..224)
  gemm256<<<dim3(16, 64, 1), b512, 0, stream>>>(eb, w1T, nullptr, hraw, nullptr, b1, nullptr,
      1, 1024, 1024, 1024, 2048, 0, 0, 0, 0, 0);

  // 9) hb = LN(hraw; ln) -> fp16 (sc region, dead)
  ln_kernel<2048><<<dim3(16384), b256, 0, stream>>>(nullptr, hraw, nullptr, lng, lnb, nullptr, hb);

  // 10) uF = leaky(hb @ w2 + b2 + eb) -> fp32 (attnb+tb region, dead)
  gemm256<<<dim3(8, 64, 1), b512, 0, stream>>>(hb, w2T, uF, nullptr, nullptr, b2, eb,
      1, 2048, 2048, 2048, 1024, 0, 0, 0, 0, 0);

  // 11) out = LN(uF; n2) fp32
  ln_kernel<1024><<<dim3(16384), b256, 0, stream>>>(uF, nullptr, nullptr, n2g, n2b, out, nullptr);
}